// Round 8
// baseline (62.313 us; speedup 1.0000x reference)
//
#include <hip/hip_runtime.h>
#include <hip/hip_bf16.h>

#define NB 16
#define NN 256
#define NH 8
#define ND 64
#define NT 5
#define HD 512   // NH*ND

typedef __bf16 bf16x8 __attribute__((ext_vector_type(8)));
typedef __bf16 bf16x4 __attribute__((ext_vector_type(4)));
typedef float  f32x4  __attribute__((ext_vector_type(4)));

__device__ __forceinline__ float4 ld4(const float* p) {
    return *reinterpret_cast<const float4*>(p);
}

__device__ __forceinline__ bf16x8 cvt8(float4 a, float4 b) {
    bf16x8 r;
    r[0] = (__bf16)a.x; r[1] = (__bf16)a.y; r[2] = (__bf16)a.z; r[3] = (__bf16)a.w;
    r[4] = (__bf16)b.x; r[5] = (__bf16)b.y; r[6] = (__bf16)b.z; r[7] = (__bf16)b.w;
    return r;
}

// fire-and-forget global->LDS (16B per lane, zero VGPR for data)
__device__ __forceinline__ void stage16(const void* g, void* l) {
    __builtin_amdgcn_global_load_lds(
        (const __attribute__((address_space(1))) void*)g,
        (__attribute__((address_space(3))) void*)l,
        16, 0, 0);
}

// Transpose a[(h*64+dd)*64*5 + e*5 + t] (fp32) -> wt[h][t][e][dd] (bf16).
__global__ void prep_w_kernel(const float* __restrict__ a, __bf16* __restrict__ wt) {
    int idx = blockIdx.x * 256 + threadIdx.x;
    if (idx >= NH * ND * ND * NT) return;
    int t  = idx % NT;
    int e  = (idx / NT) % ND;
    int dd = (idx / (NT * ND)) % ND;
    int h  = idx / (NT * ND * ND);
    wt[(((h * NT + t) * ND + e) * ND) + dd] = (__bf16)a[idx];
}

template <bool USE_WT>
__global__ __launch_bounds__(256, 2) void mhea_kernel(
    const float* __restrict__ src, const float* __restrict__ dst,
    const float* __restrict__ araw, const __bf16* __restrict__ wt,
    const int* __restrict__ edges, float* __restrict__ out)
{
    // dst tile: [jr(128)][f32 x 64], 16B-chunk c holds global chunk c^(jr&15)  (32 KB)
    __shared__ float  Dlds[128 * 64];
    // edge tile: [i(16)][int x 128], 16B-chunk c holds global chunk c^(i&7)    (8 KB)
    __shared__ int    Elds[16 * 128];
    // P: [t][i(16)][e(64)] bf16, elem ^ ((i&7)<<3)                             (10 KB)
    __shared__ __bf16 Plds[NT * 16 * 64];

    // XCD-chunked decode: each XCD (bid%8 heuristic) owns 512 consecutive wgs
    // = 2 complete b's -> ~1.3 MB working set, L2-resident.
    const int bid = blockIdx.x;
    const int wg  = (bid & 7) * 512 + (bid >> 3);   // bijective, 4096 = 8*512
    const int b   = wg >> 8;
    const int rr_ = wg & 255;
    const int it  = rr_ >> 4;
    const int h   = (rr_ >> 1) & 7;
    const int jh  = rr_ & 1;
    const int i0  = it * 16;
    const int j0  = jh * 128;

    const int tid = threadIdx.x;
    const int w   = tid >> 6;    // wave 0..3
    const int l   = tid & 63;
    const int il  = l & 15;
    const int kg  = l >> 4;      // lane k-group 0..3

    const float* dbase = dst + (size_t)b * NN * HD + h * ND;
    const float* sbase = src + (size_t)(b * NN + i0 + il) * HD + h * ND;

    // ---------------- 1) register loads FIRST (src + all wt frags) ----------------
    // (older vmcnt entries than the staging burst -> counted waits for these
    //  never force the staging queue to drain)
    float4 s0 = ld4(sbase + kg * 8);
    float4 s1 = ld4(sbase + kg * 8 + 4);
    float4 s2 = ld4(sbase + 32 + kg * 8);
    float4 s3 = ld4(sbase + 32 + kg * 8 + 4);

    const int e = w * 16 + il;   // this wave's e-tile
    bf16x8 w0[NT], w1[NT];
    if constexpr (USE_WT) {
        #pragma unroll
        for (int t = 0; t < NT; ++t) {
            const __bf16* wp = wt + (((h * NT + t) * ND + e) * ND) + kg * 8;
            w0[t] = *reinterpret_cast<const bf16x8*>(wp);
            w1[t] = *reinterpret_cast<const bf16x8*>(wp + 32);
        }
    } else {
        #pragma unroll
        for (int t = 0; t < NT; ++t) {
            #pragma unroll
            for (int jj = 0; jj < 8; ++jj) {
                w0[t][jj] = (__bf16)araw[((size_t)(h * ND + kg * 8 + jj) * ND + e) * NT + t];
                w1[t][jj] = (__bf16)araw[((size_t)(h * ND + kg * 8 + jj + 32) * ND + e) * NT + t];
            }
        }
    }

    // ---------------- 2) staging burst: dst + edges -> LDS, zero VGPR ----------------
    // D: 32 instrs (8/wave), each stages 4 rows (64 lanes x 16B = 1 KB).
    // Pre-swizzled SOURCE chunk (c ^ (jr&15)) + linear LDS dest => swizzled tile.
    #pragma unroll
    for (int k = 0; k < 8; ++k) {
        const int jrb = w * 32 + k * 4;
        const int jr  = jrb + (l >> 4);
        const int cs  = (l & 15) ^ (jr & 15);
        stage16(dbase + (size_t)(j0 + jr) * HD + cs * 4, &Dlds[jrb * 64]);
    }
    // E: 8 instrs (2/wave), each stages 2 rows (2 x 512 B).
    #pragma unroll
    for (int k = 0; k < 2; ++k) {
        const int ib = w * 4 + k * 2;
        const int i  = ib + (l >> 5);
        const int cs = (l & 31) ^ (i & 7);
        stage16(edges + ((size_t)b * NN + i0 + i) * NN + j0 + cs * 4, &Elds[ib * 128]);
    }

    // ---------------- Phase 1: P_t (swapped operands; wave's e-tile = w) ----------
    {
        bf16x8 bf0 = cvt8(s0, s1);
        bf16x8 bf1 = cvt8(s2, s3);
        #pragma unroll
        for (int t = 0; t < NT; ++t) {
            f32x4 pacc = {0.f, 0.f, 0.f, 0.f};
            pacc = __builtin_amdgcn_mfma_f32_16x16x32_bf16(w0[t], bf0, pacc, 0, 0, 0);
            pacc = __builtin_amdgcn_mfma_f32_16x16x32_bf16(w1[t], bf1, pacc, 0, 0, 0);
            bf16x4 pk;
            pk[0] = (__bf16)pacc[0];
            pk[1] = (__bf16)pacc[1];
            pk[2] = (__bf16)pacc[2];
            pk[3] = (__bf16)pacc[3];
            const int elem = (w * 16 + kg * 4) ^ ((il & 7) << 3);
            *reinterpret_cast<bf16x4*>(&Plds[t * 1024 + il * 64 + elem]) = pk;
        }
    }

    __syncthreads();   // also drains vmcnt(0) -> D/E staging complete

    // B-frags: lane (il,kg) reads P[t][il][ks*32+kg*8 .. +7]
    bf16x8 pa[NT][2];
    #pragma unroll
    for (int t = 0; t < NT; ++t) {
        #pragma unroll
        for (int ks = 0; ks < 2; ++ks) {
            const int elem = (ks * 32 + kg * 8) ^ ((il & 7) << 3);
            pa[t][ks] = *reinterpret_cast<const bf16x8*>(&Plds[t * 1024 + il * 64 + elem]);
        }
    }

    // ---------------- Phase 2: 8 j-tiles, 100% LDS-fed ----------------
    float* orow = out + (((size_t)(b * NH + h)) * NN + i0 + il) * NN + j0;

    #pragma unroll
    for (int jt = 0; jt < 8; ++jt) {
        const float* drow = &Dlds[(jt * 16 + il) * 64];
        // un-swizzle: LDS chunk (c ^ il) holds global chunk c  (jr&15 == il)
        float4 q0 = ld4(&drow[((2 * kg)     ^ il) * 4]);
        float4 q1 = ld4(&drow[((2 * kg + 1) ^ il) * 4]);
        float4 q2 = ld4(&drow[((8 + 2 * kg)     ^ il) * 4]);
        float4 q3 = ld4(&drow[((8 + 2 * kg + 1) ^ il) * 4]);
        const bf16x8 cb0 = cvt8(q0, q1);
        const bf16x8 cb1 = cvt8(q2, q3);
        const int4 ce = *reinterpret_cast<const int4*>(
            &Elds[il * 128 + (((jt * 4) + kg) ^ (il & 7)) * 4]);

        f32x4 acc[NT];
        #pragma unroll
        for (int t = 0; t < NT; ++t) {
            acc[t] = (f32x4){0.f, 0.f, 0.f, 0.f};
            acc[t] = __builtin_amdgcn_mfma_f32_16x16x32_bf16(cb0, pa[t][0], acc[t], 0, 0, 0);
            acc[t] = __builtin_amdgcn_mfma_f32_16x16x32_bf16(cb1, pa[t][1], acc[t], 0, 0, 0);
        }

        float4 o;
        #pragma unroll
        for (int r = 0; r < 4; ++r) {
            const int ev = (&ce.x)[r];
            float x;
            if (ev < 0) { x = -1e10f; }
            else {
                x = (ev == 0) ? acc[0][r]
                  : (ev == 1) ? acc[1][r]
                  : (ev == 2) ? acc[2][r]
                  : (ev == 3) ? acc[3][r]
                  :             acc[4][r];
            }
            (&o.x)[r] = (x >= 0.f) ? x : 0.2f * x;
        }
        *reinterpret_cast<float4*>(orow + jt * 16 + kg * 4) = o;
    }
}

extern "C" void kernel_launch(void* const* d_in, const int* in_sizes, int n_in,
                              void* d_out, int out_size, void* d_ws, size_t ws_size,
                              hipStream_t stream) {
    const float* src   = (const float*)d_in[0];
    const float* dst   = (const float*)d_in[1];
    const float* a     = (const float*)d_in[2];
    const int*   edges = (const int*)d_in[3];
    float* out = (float*)d_out;

    const size_t wt_bytes = (size_t)NH * NT * ND * ND * sizeof(__bf16);
    dim3 grid(4096);   // (it 16) x (h 8) x (b 16) x (jhalf 2), XCD-chunk decoded

    if (ws_size >= wt_bytes) {
        __bf16* wt = (__bf16*)d_ws;
        const int total = NH * ND * ND * NT;
        prep_w_kernel<<<(total + 255) / 256, 256, 0, stream>>>(a, wt);
        mhea_kernel<true><<<grid, 256, 0, stream>>>(src, dst, a, wt, edges, out);
    } else {
        mhea_kernel<false><<<grid, 256, 0, stream>>>(src, dst, a, nullptr, edges, out);
    }
}